// Round 15
// baseline (780.507 us; speedup 1.0000x reference)
//
#include <hip/hip_runtime.h>
#include <math.h>

#define BB 128
#define TT 512
#define HH 128
#define G4 512      // 4*H
#define CC 128
#define WW 32
#define TCHUNK 128  // time chunk (4 chunks), pipelined across launches

// ---- workspace layout (float slots) ----
#define OFF_FCWT  0                          // 16384
#define OFF_W1P   (OFF_FCWT + CC*HH)         // f16 permuted Whh1: 32768 slots
#define OFF_WI2P  (OFF_W1P  + G4*HH/2)
#define OFF_WH2P  (OFF_WI2P + G4*HH/2)
#define OFF_B1P   (OFF_WH2P + G4*HH/2)       // 512
#define OFF_WI1P  (OFF_B1P + G4)
#define OFF_B2P   (OFF_WI1P + G4)
#define OFF_H2A   (OFF_B2P + G4)             // [T][B][H] fp32
#define OFF_DOLD  (OFF_H2A + TT*BB*HH)
#define OFF_DH    (OFF_DOLD + TT*BB)
#define OFF_MT    (OFF_DH + TT*BB)
#define OFF_ST    (OFF_MT + TT)
#define OFF_C1F   (OFF_ST + TT)              // f16 [t][b][h]: TT*BB*HH/2 slots
#define OFF_C2S   (OFF_C1F + TT*BB*HH/2)     // f32 [b][h] c2 checkpoint
#define OFF_C1S   (OFF_C2S + BB*HH)          // f32 [b][h] c1 checkpoint
#define OFF_H1S   (OFF_C1S + BB*HH)          // f16 [b][h] h1 checkpoint (BB*HH/2)
#define OFF_GI2   (OFF_H1S + BB*HH/2)        // f32 x2 ping-pong: 2*TCHUNK*BB*G4
// top ~= 29.6M floats ~= 118 MB (R9/R14 executed at this size)

typedef _Float16 h2t __attribute__((ext_vector_type(2)));

__device__ __forceinline__ unsigned short f16b(float v) {
    return __builtin_bit_cast(unsigned short, (_Float16)v);
}
__device__ __forceinline__ float dot2f(unsigned int a, unsigned int b, float acc) {
#if defined(__has_builtin) && __has_builtin(__builtin_amdgcn_fdot2)
    return __builtin_amdgcn_fdot2(__builtin_bit_cast(h2t, a),
                                  __builtin_bit_cast(h2t, b), acc, false);
#else
    h2t av = __builtin_bit_cast(h2t, a), bv = __builtin_bit_cast(h2t, b);
    acc = fmaf((float)av.x, (float)bv.x, acc);
    acc = fmaf((float)av.y, (float)bv.y, acc);
    return acc;
#endif
}
__device__ __forceinline__ float rcpf(float x) {
#if defined(__has_builtin) && __has_builtin(__builtin_amdgcn_rcpf)
    return __builtin_amdgcn_rcpf(x);
#else
    return 1.f / x;
#endif
}
__device__ __forceinline__ float sigf(float v) {
    return rcpf(1.f + __expf(-v));
}
__device__ __forceinline__ float tanhf_(float v) {
    return fmaf(2.f, rcpf(1.f + __expf(-2.f * v)), -1.f);
}

// DPP quad_perm helpers (pure VALU, quad-local).
template <int CTRL>
__device__ __forceinline__ float dppadd(float v) {
#if defined(__has_builtin) && __has_builtin(__builtin_amdgcn_update_dpp)
    int m = __builtin_amdgcn_update_dpp(0, __builtin_bit_cast(int, v),
                                        CTRL, 0xf, 0xf, true);
    return v + __builtin_bit_cast(float, m);
#else
    return v + __shfl_xor(v, CTRL == 0xB1 ? 1 : 2);
#endif
}
__device__ __forceinline__ float qsum(float v) {
    v = dppadd<0xB1>(v);
    v = dppadd<0x4E>(v);
    return v;
}

// 32 dot2: one 64-col row-slice (8 uint4 f16 weights) x state (8 uint4)
__device__ __forceinline__ void dot32(float& acc, const uint4* W, const uint4* S) {
    #pragma unroll
    for (int k = 0; k < 8; ++k) {
        acc = dot2f(W[k].x, S[k].x, acc);
        acc = dot2f(W[k].y, S[k].y, acc);
        acc = dot2f(W[k].z, S[k].z, acc);
        acc = dot2f(W[k].w, S[k].w, acc);
    }
}
// 16 dot2: one 32-col row-slice (4 uint4 f16 weights) x state (4 uint4)
__device__ __forceinline__ float dotrow32(const uint4* W, const uint4* S) {
    float acc = 0.f;
    #pragma unroll
    for (int k = 0; k < 4; ++k) {
        acc = dot2f(W[k].x, S[k].x, acc);
        acc = dot2f(W[k].y, S[k].y, acc);
        acc = dot2f(W[k].z, S[k].z, acc);
        acc = dot2f(W[k].w, S[k].w, acc);
    }
    return acc;
}

// LDS-visibility barrier WITHOUT vmcnt drain.
#define STEP_BARRIER() asm volatile("s_waitcnt lgkmcnt(0)\n\ts_barrier" ::: "memory")

// K0: gate-interleaved (r = h*4 + g) f16 weight images + permuted biases +
// fcW transpose.  (unchanged)
__global__ __launch_bounds__(256) void k0_prep(
    const float* __restrict__ Whh1, const float* __restrict__ Wih2,
    const float* __restrict__ Whh2, const float* __restrict__ fcW,
    const float* __restrict__ Wih1,
    const float* __restrict__ bih1, const float* __restrict__ bhh1,
    const float* __restrict__ bih2, const float* __restrict__ bhh2,
    float* __restrict__ fcWT,
    unsigned short* __restrict__ w1p, unsigned short* __restrict__ wi2p,
    unsigned short* __restrict__ wh2p,
    float* __restrict__ b1p, float* __restrict__ wi1p, float* __restrict__ b2p)
{
    int idx = blockIdx.x * blockDim.x + threadIdx.x;
    if (idx < G4 * HH) {
        int r_old = idx >> 7, k = idx & 127;
        int g = r_old >> 7, h = r_old & 127;
        int dst = (h * 4 + g) * HH + k;
        w1p [dst] = f16b(Whh1[idx]);
        wi2p[dst] = f16b(Wih2[idx]);
        wh2p[dst] = f16b(Whh2[idx]);
    }
    if (idx < CC * HH) {
        int c = idx / HH, h = idx % HH;
        fcWT[h * CC + c] = fcW[idx];
    }
    if (idx < G4) {
        int g = idx >> 7, h = idx & 127;
        int rn = h * 4 + g;
        b1p [rn] = bih1[idx] + bhh1[idx];
        wi1p[rn] = Wih1[idx];
        b2p [rn] = bih2[idx] + bhh2[idx];
    }
}

// K1AC: pipelined fused kernel (R14 structure).  The C-role gi2 read is now
// 4-DEEP PREFETCHED (named g0..g3, static indexing): R14's counters showed
// middle launches at 138us vs the ~95us role arithmetic, with hbm_bytes ==
// exactly the gi2 write+read stream -- the 1-deep prefetch ate a cross-XCD
// L3/HBM miss (~300-900cy) per ~600cy step.  Distance-4 covers it.
__global__ __launch_bounds__(512)
__attribute__((amdgpu_waves_per_eu(2, 2)))
void k1ac(
    const float* __restrict__ x,
    const float* __restrict__ b1p, const float* __restrict__ wi1p,
    const unsigned short* __restrict__ w1p,
    const unsigned short* __restrict__ wi2p, const float* __restrict__ b2p,
    const unsigned short* __restrict__ wh2p,
    unsigned short* __restrict__ c1f, float* __restrict__ c1s,
    unsigned short* __restrict__ h1s,
    float* __restrict__ h2a, float* __restrict__ c2s,
    float* __restrict__ gi2a, const float* __restrict__ gi2c,
    int t0a, int t0c)
{
    __shared__ __align__(16) unsigned short h1h[2][HH];   // A-role
    __shared__ float xs[TCHUNK];                          // A-role
    __shared__ __align__(16) unsigned short c1t[16][HH];  // A-role B-tail
    __shared__ __align__(16) unsigned short h2h[2][HH];   // C-role

    const int tid = threadIdx.x;
    const bool hasA = (t0a >= 0);

    if (hasA && (int)blockIdx.x < BB) {
        // ================= A-role: layer-1 chunk + B-tail =================
        const int b = blockIdx.x;
        const int s = tid & 3;             // 32-col slice
        const int h = tid >> 2;            // unit 0..127

        uint4 w1[4][4];
        float wi1v[4], b1v[4];
        #pragma unroll
        for (int r = 0; r < 4; ++r) {
            const uint4* p1 = (const uint4*)(w1p + (size_t)(4 * h + r) * HH + 32 * s);
            #pragma unroll
            for (int k = 0; k < 4; ++k) w1[r][k] = p1[k];
            wi1v[r] = wi1p[4 * h + r];
            b1v[r]  = b1p [4 * h + r];
        }

        if (tid < TCHUNK) xs[tid] = x[(size_t)b * TT + t0a + tid];
        float c1reg;
        if (t0a == 0) {
            if (tid < HH) { h1h[0][tid] = 0; }
            c1reg = 0.f;
        } else {
            if (tid < HH) h1h[0][tid] = h1s[b * HH + tid];
            c1reg = c1s[b * HH + h];
        }
        __syncthreads();

        unsigned short* outc = c1f + ((size_t)t0a * BB + b) * HH + h;

        for (int ts = 0; ts < TCHUNK; ++ts) {
            const int p = ts & 1, q = p ^ 1;
            const float xv = xs[ts];

            uint4 sv[4];
            const uint4* hp = (const uint4*)&h1h[p][32 * s];
            #pragma unroll
            for (int k = 0; k < 4; ++k) sv[k] = hp[k];
            float a0 = dotrow32(w1[0], sv);
            float a1 = dotrow32(w1[1], sv);
            float a2 = dotrow32(w1[2], sv);
            float a3 = dotrow32(w1[3], sv);
            a0 = qsum(a0); a1 = qsum(a1); a2 = qsum(a2); a3 = qsum(a3);

            float gi = a0 + fmaf(xv, wi1v[0], b1v[0]);
            float gf = a1 + fmaf(xv, wi1v[1], b1v[1]);
            float gg = a2 + fmaf(xv, wi1v[2], b1v[2]);
            float go = a3 + fmaf(xv, wi1v[3], b1v[3]);
            float cn = sigf(gf) * c1reg + sigf(gi) * tanhf_(gg);
            c1reg = cn;
            float hn = sigf(go) * tanhf_(cn);
            if (s == 0) {
                h1h[q][h] = f16b(hn);
                outc[(size_t)ts * (BB * HH)] = f16b(cn);
                if (ts == TCHUNK - 1) h1s[b * HH + h] = f16b(hn);
            }
            STEP_BARRIER();
        }
        if (s == 0) c1s[b * HH + h] = c1reg;   // exact f32 checkpoint

        // ---- B-tail: gi2a[b][tc][r] = b2[r] + Wih2[r,:].c1[t0a+tc,b,:] ----
        asm volatile("s_waitcnt vmcnt(0)" ::: "memory");
        const int rq = tid >> 1;           // rows 2rq, 2rq+1
        const int sB = tid & 1;            // col half
        uint4 wa[8], wb[8];
        {
            const uint4* pa = (const uint4*)(wi2p + (size_t)(2 * rq) * HH + 64 * sB);
            const uint4* pb = (const uint4*)(wi2p + (size_t)(2 * rq + 1) * HH + 64 * sB);
            #pragma unroll
            for (int k = 0; k < 8; ++k) { wa[k] = pa[k]; wb[k] = pb[k]; }
        }
        const float bias = b2p[2 * rq + sB];
        float* gout = gi2a + (size_t)b * TCHUNK * G4;
        for (int tg = 0; tg < TCHUNK; tg += 16) {
            __syncthreads();
            {
                int row = tid >> 5;        // 0..15
                int col = (tid & 31) * 4;  // halfwords
                *(uint2*)&c1t[row][col] =
                    *(const uint2*)(c1f + ((size_t)(t0a + tg + row) * BB + b) * HH + col);
            }
            __syncthreads();
            #pragma unroll 4
            for (int tt = 0; tt < 16; ++tt) {
                uint4 sv[8];
                const uint4* cp = (const uint4*)&c1t[tt][64 * sB];
                #pragma unroll
                for (int k = 0; k < 8; ++k) sv[k] = cp[k];
                float d0 = 0.f, d1 = 0.f;
                dot32(d0, wa, sv);
                dot32(d1, wb, sv);
                float D0 = dppadd<0xB1>(d0);
                float D1 = dppadd<0xB1>(d1);
                float v  = (sB ? D1 : D0) + bias;
                gout[(size_t)(tg + tt) * G4 + 2 * rq + sB] = v;
            }
        }
    } else {
        // ================= C-role: layer-2 chunk, 4-deep gi2 prefetch =====
        const int b = blockIdx.x - (hasA ? BB : 0);
        const int s = tid & 3;
        const int h = tid >> 2;
        const int t0 = t0c;

        uint4 w2[4][4];
        #pragma unroll
        for (int r = 0; r < 4; ++r) {
            const uint4* p1 = (const uint4*)(wh2p + (size_t)(4 * h + r) * HH + 32 * s);
            #pragma unroll
            for (int k = 0; k < 4; ++k) w2[r][k] = p1[k];
        }

        if (tid < HH) {
            unsigned short hv = 0;
            if (t0 > 0) hv = f16b(h2a[((size_t)(t0 - 1) * BB + b) * HH + tid]);
            h2h[0][tid] = hv;
            h2h[1][tid] = 0;
        }
        float c2reg = (t0 > 0) ? c2s[b * HH + h] : 0.f;
        __syncthreads();

        const float* gbase = gi2c + (size_t)b * TCHUNK * G4 + 4 * h;
        float* outp = h2a + (size_t)b * HH + h;

        #define GLD(TS) (*(const float4*)(gbase + (size_t)(TS) * G4))
        #define CSTEP(TSV, GREG) do {                                        \
            const int p_ = (TSV) & 1, q_ = p_ ^ 1;                           \
            uint4 sv_[4];                                                    \
            const uint4* hp_ = (const uint4*)&h2h[p_][32 * s];               \
            _Pragma("unroll")                                                \
            for (int k_ = 0; k_ < 4; ++k_) sv_[k_] = hp_[k_];                \
            float a0_ = dotrow32(w2[0], sv_);                                \
            float a1_ = dotrow32(w2[1], sv_);                                \
            float a2_ = dotrow32(w2[2], sv_);                                \
            float a3_ = dotrow32(w2[3], sv_);                                \
            a0_ = qsum(a0_); a1_ = qsum(a1_);                                \
            a2_ = qsum(a2_); a3_ = qsum(a3_);                                \
            float gi_ = a0_ + (GREG).x;                                      \
            float gf_ = a1_ + (GREG).y;                                      \
            float gg_ = a2_ + (GREG).z;                                      \
            float go_ = a3_ + (GREG).w;                                      \
            float cn_ = sigf(gf_) * c2reg + sigf(gi_) * tanhf_(gg_);         \
            c2reg = cn_;                                                     \
            float hn_ = sigf(go_) * tanhf_(cn_);                             \
            if (s == 0) {                                                    \
                h2h[q_][h] = f16b(hn_);                                      \
                outp[(size_t)(t0 + (TSV)) * (BB * HH)] = hn_;                \
            }                                                                \
            STEP_BARRIER();                                                  \
        } while (0)

        const float4 fz = make_float4(0.f, 0.f, 0.f, 0.f);
        float4 g0 = GLD(0), g1 = GLD(1), g2 = GLD(2), g3 = GLD(3);
        for (int ts = 0; ts < TCHUNK; ts += 4) {
            CSTEP(ts + 0, g0); g0 = (ts + 4 < TCHUNK) ? GLD(ts + 4) : fz;
            CSTEP(ts + 1, g1); g1 = (ts + 5 < TCHUNK) ? GLD(ts + 5) : fz;
            CSTEP(ts + 2, g2); g2 = (ts + 6 < TCHUNK) ? GLD(ts + 6) : fz;
            CSTEP(ts + 3, g3); g3 = (ts + 7 < TCHUNK) ? GLD(ts + 7) : fz;
        }
        #undef CSTEP
        #undef GLD
        if (s == 0) c2s[b * HH + h] = c2reg;
    }
}

// K2: d_old[t,b] = h2[t,b,:].wt_old ; d_h[t,b] = h2[t,b,:].wt_h  (unchanged)
__global__ __launch_bounds__(256) void k2_dots(
    const float* __restrict__ h2a, const float* __restrict__ w_t,
    float* __restrict__ dold, float* __restrict__ dh)
{
    const int lane = threadIdx.x & 63;
    const int wave = blockIdx.x * (blockDim.x >> 6) + (threadIdx.x >> 6);
    const int nw = gridDim.x * (blockDim.x >> 6);
    const float wh0 = w_t[lane],       wh1 = w_t[64 + lane];
    const float wo0 = w_t[128 + lane], wo1 = w_t[192 + lane];
    for (int row = wave; row < TT * BB; row += nw) {
        const float* p = h2a + (size_t)row * HH;
        float v0 = p[lane], v1 = p[64 + lane];
        float po = v0 * wo0 + v1 * wo1;
        float ph = v0 * wh0 + v1 * wh1;
        #pragma unroll
        for (int off = 32; off; off >>= 1) {
            po += __shfl_xor(po, off);
            ph += __shfl_xor(ph, off);
        }
        if (lane == 0) { dold[row] = po; dh[row] = ph; }
    }
}

// K3: per-t global softmax stats over valid (j,b): m[t], s[t]  (unchanged)
__global__ __launch_bounds__(256) void k3_stats(
    const float* __restrict__ dold, const float* __restrict__ dh,
    float* __restrict__ mt, float* __restrict__ st)
{
    const int t = blockIdx.x;
    const int tid = threadIdx.x;
    const int cnt = (min(t, WW) + 1) * BB;
    const int jstart = max(t - (WW + 1), -1);

    float m = -INFINITY;
    for (int idx = tid; idx < cnt; idx += 256) {
        int jj = idx >> 7, b = idx & 127;
        int j = jstart + jj;
        float sc = dh[t * BB + b] + (j >= 0 ? dold[j * BB + b] : 0.f);
        m = fmaxf(m, sc);
    }
    #pragma unroll
    for (int off = 32; off; off >>= 1) m = fmaxf(m, __shfl_xor(m, off));
    __shared__ float rbuf[4];
    int wv = tid >> 6, ln = tid & 63;
    if (ln == 0) rbuf[wv] = m;
    __syncthreads();
    m = fmaxf(fmaxf(rbuf[0], rbuf[1]), fmaxf(rbuf[2], rbuf[3]));

    float s = 0.f;
    for (int idx = tid; idx < cnt; idx += 256) {
        int jj = idx >> 7, b = idx & 127;
        int j = jstart + jj;
        float sc = dh[t * BB + b] + (j >= 0 ? dold[j * BB + b] : 0.f);
        s += __expf(sc - m);
    }
    #pragma unroll
    for (int off = 32; off; off >>= 1) s += __shfl_xor(s, off);
    __shared__ float sbuf[4];
    if (ln == 0) sbuf[wv] = s;
    __syncthreads();
    if (tid == 0) { mt[t] = m; st[t] = sbuf[0] + sbuf[1] + sbuf[2] + sbuf[3]; }
}

// K45: fused attention + FC. grid (TT/8, BB), block 256.  (unchanged)
__global__ __launch_bounds__(256) void k45_attn_fc(
    const float* __restrict__ h2a,
    const float* __restrict__ dold, const float* __restrict__ dh,
    const float* __restrict__ mt, const float* __restrict__ st,
    const float* __restrict__ fcWT, const float* __restrict__ fcb,
    float* __restrict__ out)
{
    const int t0 = blockIdx.x * 8;
    const int b  = blockIdx.y;
    const int tid = threadIdx.x;

    __shared__ float hbuf[41][HH];     // rows t0-33 .. t0+7
    __shared__ float wjs[8][36];
    __shared__ float ytile[8][HH];

    for (int i = tid; i < 41 * 32; i += 256) {
        int r = i >> 5, q4 = i & 31;
        int t = t0 - 33 + r;
        float4 v = make_float4(0.f, 0.f, 0.f, 0.f);
        if (t >= 0)
            v = *(const float4*)(h2a + (size_t)t * (BB * HH) + (size_t)b * HH + q4 * 4);
        *(float4*)&hbuf[r][q4 * 4] = v;
    }
    for (int i = tid; i < 8 * 33; i += 256) {
        int tt = i / 33, ss = i % 33;
        int t = t0 + tt, j = t - 33 + ss;
        float w = 0.f;
        if (j >= 0)
            w = __expf(dold[j * BB + b] + dh[t * BB + b] - mt[t]) / st[t];
        wjs[tt][ss] = w;
    }
    __syncthreads();

    {
        const int tq = tid >> 5;
        const int hq = (tid & 31) * 4;
        float4 acc = *(const float4*)&hbuf[tq + 33][hq];   // h2[t]
        #pragma unroll 11
        for (int ss = 0; ss < 33; ++ss) {
            float w = wjs[tq][ss];
            float4 hb = *(const float4*)&hbuf[tq + ss][hq];
            acc.x = fmaf(w, hb.x, acc.x);
            acc.y = fmaf(w, hb.y, acc.y);
            acc.z = fmaf(w, hb.z, acc.z);
            acc.w = fmaf(w, hb.w, acc.w);
        }
        *(float4*)&ytile[tq][hq] = acc;
    }
    __syncthreads();

    {
        const int c  = tid & 127;
        const int th = tid >> 7;
        float acc[4];
        const float bias = fcb[c];
        #pragma unroll
        for (int i = 0; i < 4; ++i) acc[i] = bias;
        for (int hh = 0; hh < HH; ++hh) {
            float w = fcWT[hh * CC + c];
            #pragma unroll
            for (int i = 0; i < 4; ++i)
                acc[i] = fmaf(ytile[th * 4 + i][hh], w, acc[i]);
        }
        #pragma unroll
        for (int i = 0; i < 4; ++i) {
            int t = t0 + th * 4 + i;
            out[(size_t)b * (TT * CC) + (size_t)t * CC + c] = acc[i];
        }
    }
}

extern "C" void kernel_launch(void* const* d_in, const int* in_sizes, int n_in,
                              void* d_out, int out_size, void* d_ws, size_t ws_size,
                              hipStream_t stream)
{
    const float* x    = (const float*)d_in[0];
    const float* Wih1 = (const float*)d_in[1];
    const float* Whh1 = (const float*)d_in[2];
    const float* bih1 = (const float*)d_in[3];
    const float* bhh1 = (const float*)d_in[4];
    const float* Wih2 = (const float*)d_in[5];
    const float* Whh2 = (const float*)d_in[6];
    const float* bih2 = (const float*)d_in[7];
    const float* bhh2 = (const float*)d_in[8];
    const float* w_t  = (const float*)d_in[9];
    const float* fcW  = (const float*)d_in[10];
    const float* fcb  = (const float*)d_in[11];
    float* out = (float*)d_out;

    float* ws   = (float*)d_ws;
    float* fcWT = ws + OFF_FCWT;
    unsigned short* w1p  = (unsigned short*)(ws + OFF_W1P);
    unsigned short* wi2p = (unsigned short*)(ws + OFF_WI2P);
    unsigned short* wh2p = (unsigned short*)(ws + OFF_WH2P);
    float* b1pp = ws + OFF_B1P;
    float* wi1p = ws + OFF_WI1P;
    float* b2pp = ws + OFF_B2P;
    float* h2a  = ws + OFF_H2A;
    float* dold = ws + OFF_DOLD;
    float* dh   = ws + OFF_DH;
    float* mt   = ws + OFF_MT;
    float* st   = ws + OFF_ST;
    unsigned short* c1f = (unsigned short*)(ws + OFF_C1F);
    float* c2s  = ws + OFF_C2S;
    float* c1s  = ws + OFF_C1S;
    unsigned short* h1s = (unsigned short*)(ws + OFF_H1S);
    float* gi2b0 = ws + OFF_GI2;
    float* gi2b1 = gi2b0 + (size_t)TCHUNK * BB * G4;

    k0_prep<<<dim3((G4 * HH + 255) / 256), dim3(256), 0, stream>>>(
        Whh1, Wih2, Whh2, fcW, Wih1, bih1, bhh1, bih2, bhh2,
        fcWT, w1p, wi2p, wh2p, b1pp, wi1p, b2pp);

    // Pipeline: [A0B0] -> [A1B1|C0] -> [A2B2|C1] -> [A3B3|C2] -> [C3]
    float* bufs[2] = { gi2b0, gi2b1 };
    k1ac<<<dim3(BB), dim3(512), 0, stream>>>(
        x, b1pp, wi1p, w1p, wi2p, b2pp, wh2p,
        c1f, c1s, h1s, h2a, c2s, bufs[0], bufs[1], 0, -1);
    for (int i = 1; i < 4; ++i) {
        k1ac<<<dim3(2 * BB), dim3(512), 0, stream>>>(
            x, b1pp, wi1p, w1p, wi2p, b2pp, wh2p,
            c1f, c1s, h1s, h2a, c2s,
            bufs[i & 1], bufs[(i - 1) & 1],
            i * TCHUNK, (i - 1) * TCHUNK);
    }
    k1ac<<<dim3(BB), dim3(512), 0, stream>>>(
        x, b1pp, wi1p, w1p, wi2p, b2pp, wh2p,
        c1f, c1s, h1s, h2a, c2s, bufs[0], bufs[1], -1, 3 * TCHUNK);

    k2_dots<<<dim3(256), dim3(256), 0, stream>>>(h2a, w_t, dold, dh);

    k3_stats<<<dim3(TT), dim3(256), 0, stream>>>(dold, dh, mt, st);

    k45_attn_fc<<<dim3(TT / 8, BB), dim3(256), 0, stream>>>(
        h2a, dold, dh, mt, st, fcWT, fcb, out);
}